// Round 1
// baseline (419.857 us; speedup 1.0000x reference)
//
#include <hip/hip_runtime.h>
#include <math.h>
#include <stdint.h>

// Problem constants: BS=16, SEQ=1024, NV=512, DM=256, K=8
#define BS 16
#define SEQ 1024
#define NV 512
#define DM 256
#define NK 8

// ---------------------------------------------------------------------------
// Module-global scratch. Every launch fully overwrites before reading
// (stream-ordered producer->consumer), so graph replay is self-contained.
// g_zp (134 MB fp32 K-split partials) is GONE: the K-split now lives inside
// the gemm block and partials combine through LDS.
// ---------------------------------------------------------------------------
__device__ double g_WC[NK * SEQ];                          // 64 KB
__device__ double g_Bk[NK];                                // 64 B
__device__ __align__(16) float g_Wt[SEQ * DM];             // 1 MB  [s][d]
__device__ double g_nn2[BS * NV];                          // 64 KB
__device__ double g_Dp[8 * BS * NV * NK];                  // 4 MB [sc][b][v][k]
__device__ unsigned char g_bits[BS * NV];                  // 8 KB

// ---------------------------------------------------------------------------
// Exact JAX threefry2x32 (20 rounds), key = PRNGKey(7) = (0, 7).
// ---------------------------------------------------------------------------
__device__ __forceinline__ void threefry2x32_key7(uint32_t x0, uint32_t x1,
                                                  uint32_t& o0, uint32_t& o1) {
    const uint32_t k0 = 0u, k1 = 7u;
    const uint32_t k2 = k0 ^ k1 ^ 0x1BD11BDAu;
    uint32_t v0 = x0 + k0, v1 = x1 + k1;
#define TF_ROUND(r) { v0 += v1; v1 = (v1 << (r)) | (v1 >> (32 - (r))); v1 ^= v0; }
    TF_ROUND(13) TF_ROUND(15) TF_ROUND(26) TF_ROUND(6)
    v0 += k1; v1 += k2 + 1u;
    TF_ROUND(17) TF_ROUND(29) TF_ROUND(16) TF_ROUND(24)
    v0 += k2; v1 += k0 + 2u;
    TF_ROUND(13) TF_ROUND(15) TF_ROUND(26) TF_ROUND(6)
    v0 += k0; v1 += k1 + 3u;
    TF_ROUND(17) TF_ROUND(29) TF_ROUND(16) TF_ROUND(24)
    v0 += k1; v1 += k2 + 4u;
    TF_ROUND(13) TF_ROUND(15) TF_ROUND(26) TF_ROUND(6)
    v0 += k2; v1 += k0 + 5u;
#undef TF_ROUND
    o0 = v0; o1 = v1;
}

__device__ __forceinline__ float bits_to_uniform(uint32_t b) {
    return __uint_as_float((b >> 9) | 0x3F800000u) - 1.0f;
}

// ---------------------------------------------------------------------------
// W transpose: g_Wt[s][d] = W[d][s]. Grid (sblk 16, dblk 2) = 32 blocks.
// Tile 64 s x 128 d via LDS; both sides coalesced.
// ---------------------------------------------------------------------------
__global__ __launch_bounds__(256) void wt_kernel(const float* __restrict__ W) {
    __shared__ float tile[64][132];
    const int t = threadIdx.x;
    const int s0 = blockIdx.x * 64;
    const int d0 = blockIdx.y * 128;
#pragma unroll
    for (int p = 0; p < 32; ++p) {
        int lin = p * 256 + t;
        int d = lin >> 6, s = lin & 63;          // read coalesced over s
        tile[s][d] = W[(size_t)(d0 + d) * SEQ + s0 + s];
    }
    __syncthreads();
#pragma unroll
    for (int p = 0; p < 32; ++p) {
        int lin = p * 256 + t;
        int s = lin >> 7, d = lin & 127;         // write coalesced over d
        g_Wt[(size_t)(s0 + s) * DM + d0 + d] = tile[s][d];
    }
}

// ---------------------------------------------------------------------------
// Prep: WC, Bk in fp64. unroll 8 on the d-loop so the L2 loads pipeline
// (32 blocks -> 1 wave/SIMD, no TLP to hide latency otherwise).
// ---------------------------------------------------------------------------
__global__ __launch_bounds__(256) void prep_kernel(
        const float* __restrict__ W, const float* __restrict__ bias,
        const float* __restrict__ ce) {
    __shared__ double red[256];
    __shared__ double cen[256];
    const int t = threadIdx.x;
    const int k = blockIdx.x >> 2;
    const int schunk = blockIdx.x & 3;

    double c = (double)ce[k * DM + t];
    red[t] = c * c;
    __syncthreads();
    for (int off = 128; off > 0; off >>= 1) {
        if (t < off) red[t] += red[t + off];
        __syncthreads();
    }
    double nc = fmax(sqrt(red[0]), 1e-12);
    cen[t] = c / nc;
    __syncthreads();
    red[t] = (double)bias[t] * cen[t];
    __syncthreads();
    for (int off = 128; off > 0; off >>= 1) {
        if (t < off) red[t] += red[t + off];
        __syncthreads();
    }
    if (t == 0 && schunk == 0) g_Bk[k] = red[0];

    const int s = schunk * 256 + t;
    double acc = 0.0;
#pragma unroll 8
    for (int d = 0; d < DM; ++d)
        acc += cen[d] * (double)W[(size_t)d * SEQ + s];
    g_WC[(size_t)k * SEQ + s] = acc;
}

// ---------------------------------------------------------------------------
// Fused GEMM + nn2: grid (vblk 16, b 16) = 256 blocks = 1 block/CU.
// Block tile 32v x 256d, 256 threads = 4 waves; wave w owns K-range
// [256w, 256w+256) (the old cross-block kblk split, now in-block).
// Lane layout: vg = lane>>4 (4 groups of 8 v), dg = lane&15 (16 groups of
// 16 d) -> thread tile 8v x 16d = 128 acc (0.75 B LDS per MAC, same as
// the proven 128x256 tile). LDS: wst 4x32x256 (128 KB, quad-XOR swizzled
// so the dg*16 b128 reads are 2-way = free) + xs 4x32x32 (16 KB) = 144 KB.
// Epilogue: waves 1..3 dump fp32 partials to LDS (132-pad stride,
// conflict-free); wave 0 combines in fp64 with the exact same promotion
// order as the old combine_kernel ((((p0+p1)+p2)+p3)+bias), squares,
// reduces over dg, writes g_nn2 directly. 268 MB of g_zp HBM traffic gone.
// ---------------------------------------------------------------------------
__global__ __launch_bounds__(256, 1) void gemm_kernel(
        const float* __restrict__ x, const float* __restrict__ bias) {
    __shared__ __align__(16) float smem[36864];   // 144 KB
    float* const s_wst = smem;                    // [4][32][256] swizzled
    float* const s_xs  = smem + 32768;            // [4][32][32]

    const int t    = threadIdx.x;
    const int v0   = blockIdx.x * 32;
    const int b    = blockIdx.y;
    const int w    = t >> 6;        // wave = kgroup 0..3
    const int lane = t & 63;
    const int vg   = lane >> 4;     // 0..3
    const int dg   = lane & 15;     // 0..15
    const int xsw  = (dg >> 1) & 3; // quad swizzle key
    const int wo0  = dg * 16 + ((0 ^ xsw) << 2);  // stored pos of orig quad 0
    const int wo1  = dg * 16 + ((1 ^ xsw) << 2);
    const int wo2  = dg * 16 + ((2 ^ xsw) << 2);
    const int wo3  = dg * 16 + ((3 ^ xsw) << 2);

    const float* const xb = x + (size_t)b * SEQ * NV + v0;

    float acc[8][16];
#pragma unroll
    for (int j = 0; j < 8; ++j)
#pragma unroll
        for (int i = 0; i < 16; ++i) acc[j][i] = 0.0f;

    for (int so = 0; so < 256; so += 32) {   // 8 outer iters
        __syncthreads();
        // stage xs: 4 kgroups x 32 s x 32 v (1024 float4, 4/thread)
#pragma unroll
        for (int j = 0; j < 4; ++j) {
            int f = j * 256 + t;
            int kg = f >> 8, sl = (f >> 3) & 31, c4 = (f & 7) << 2;
            float4 val = *(const float4*)&xb[(size_t)(kg * 256 + so + sl) * NV + c4];
            *(float4*)&s_xs[(kg * 32 + sl) * 32 + c4] = val;
        }
        // stage wst: 4 kgroups x 32 s x 256 d (8192 float4, 32/thread);
        // each wave-pass reads one full 1 KB Wt row (L2-resident, 1 MB).
#pragma unroll
        for (int j = 0; j < 32; ++j) {
            int f = j * 256 + t;
            int kg = f >> 11, sl = (f >> 6) & 31, c4 = (f & 63) << 2;
            float4 val = *(const float4*)&g_Wt[(size_t)(kg * 256 + so + sl) * DM + c4];
            int sc = c4 ^ (((c4 >> 5) & 3) << 2);   // quad XOR swizzle
            *(float4*)&s_wst[(kg * 32 + sl) * 256 + sc] = val;
        }
        __syncthreads();

        const float* xrow = &s_xs[(w * 32) * 32 + vg * 8];
        const float* wrow = &s_wst[(w * 32) * 256];
#pragma unroll
        for (int kk = 0; kk < 32; ++kk) {
            float4 xv0 = *(const float4*)(xrow);
            float4 xv1 = *(const float4*)(xrow + 4);
            float4 wq0 = *(const float4*)(wrow + wo0);
            float4 wq1 = *(const float4*)(wrow + wo1);
            float4 wq2 = *(const float4*)(wrow + wo2);
            float4 wq3 = *(const float4*)(wrow + wo3);
            float xv[8]  = {xv0.x, xv0.y, xv0.z, xv0.w, xv1.x, xv1.y, xv1.z, xv1.w};
            float wv[16] = {wq0.x, wq0.y, wq0.z, wq0.w, wq1.x, wq1.y, wq1.z, wq1.w,
                            wq2.x, wq2.y, wq2.z, wq2.w, wq3.x, wq3.y, wq3.z, wq3.w};
#pragma unroll
            for (int j = 0; j < 8; ++j)
#pragma unroll
                for (int i = 0; i < 16; ++i) acc[j][i] += xv[j] * wv[i];
            xrow += 32;
            wrow += 256;
        }
    }

    // ---- in-block K-combine + nn2 ----
    __syncthreads();
    if (w > 0) {   // waves 1..3 park fp32 partials (132-float stride: pad)
        float* dst = &s_wst[((w - 1) * 64 + lane) * 132];
#pragma unroll
        for (int j = 0; j < 8; ++j)
#pragma unroll
            for (int m = 0; m < 16; m += 4)
                *(float4*)&dst[j * 16 + m] =
                    make_float4(acc[j][m], acc[j][m + 1], acc[j][m + 2], acc[j][m + 3]);
    }
    __syncthreads();
    if (w == 0) {  // wave 0: exact fp64 combine, same order as old combine_kernel
        const float* p1 = &s_wst[(0 * 64 + lane) * 132];
        const float* p2 = &s_wst[(1 * 64 + lane) * 132];
        const float* p3 = &s_wst[(2 * 64 + lane) * 132];
        double* dred = (double*)(smem + 33792);   // 512 doubles, old xs area
        double sqv[8];
#pragma unroll
        for (int j = 0; j < 8; ++j) sqv[j] = 0.0;
#pragma unroll
        for (int j = 0; j < 8; ++j) {
#pragma unroll
            for (int m = 0; m < 16; m += 4) {
                float4 q1 = *(const float4*)&p1[j * 16 + m];
                float4 q2 = *(const float4*)&p2[j * 16 + m];
                float4 q3 = *(const float4*)&p3[j * 16 + m];
                float4 bb = *(const float4*)&bias[dg * 16 + m];
                double z0 = (double)acc[j][m]     + (double)q1.x + (double)q2.x + (double)q3.x + (double)bb.x;
                double z1 = (double)acc[j][m + 1] + (double)q1.y + (double)q2.y + (double)q3.y + (double)bb.y;
                double z2 = (double)acc[j][m + 2] + (double)q1.z + (double)q2.z + (double)q3.z + (double)bb.z;
                double z3 = (double)acc[j][m + 3] + (double)q1.w + (double)q2.w + (double)q3.w + (double)bb.w;
                sqv[j] += z0 * z0 + z1 * z1 + z2 * z2 + z3 * z3;
            }
        }
#pragma unroll
        for (int j = 0; j < 8; ++j)
            dred[(vg * 8 + j) * 16 + dg] = sqv[j];
    }
    __syncthreads();
    if (t < 32) {
        const double* dred = (const double*)(smem + 33792);
        double s = 0.0;
#pragma unroll
        for (int i = 0; i < 16; ++i) s += dred[t * 16 + i];
        g_nn2[b * NV + v0 + t] = s;
    }
}

// ---------------------------------------------------------------------------
// D-kernel (unchanged): D_k partials over 128-s chunks, fp64.
// Grid: (vblk=8, b=16, sc=8) = 1024 blocks.
// ---------------------------------------------------------------------------
__global__ __launch_bounds__(256) void dkern(const float* __restrict__ x) {
    __shared__ double wcd[NK][128];
    __shared__ double dw[4][64][NK];
    const int t = threadIdx.x;
    const int vblk = blockIdx.x;
    const int b    = blockIdx.y;
    const int sc   = blockIdx.z;
    const int v0 = vblk * 64;
    const int ss = sc * 128;

#pragma unroll
    for (int j = 0; j < 4; ++j) {
        int idx = j * 256 + t;
        ((double*)wcd)[idx] = g_WC[(size_t)(idx >> 7) * SEQ + ss + (idx & 127)];
    }
    __syncthreads();

    const int vl = t & 63, w = t >> 6;
    const float* xp = x + (size_t)b * SEQ * NV + v0 + vl;
    double D[NK];
#pragma unroll
    for (int k = 0; k < NK; ++k) D[k] = 0.0;
    const int sw = w * 32;
    for (int i = 0; i < 32; ++i) {
        int sl = sw + i;
        double xv = (double)xp[(size_t)(ss + sl) * NV];
#pragma unroll
        for (int k = 0; k < NK; ++k) D[k] += xv * wcd[k][sl];
    }
#pragma unroll
    for (int k = 0; k < NK; ++k) dw[w][vl][k] = D[k];
    __syncthreads();

    const int v = t & 63, k2 = (t >> 6) * 2;
#pragma unroll
    for (int j = 0; j < 2; ++j) {
        int k = k2 + j;
        double s = dw[0][v][k] + dw[1][v][k] + dw[2][v][k] + dw[3][v][k];
        g_Dp[(((size_t)sc * BS + b) * NV + v0 + v) * NK + k] = s;
    }
}

// ---------------------------------------------------------------------------
// Finalize (unchanged): sinkhorn softmax fp64, partitionable threefry, bits.
// ---------------------------------------------------------------------------
__global__ __launch_bounds__(256) void finalize_kernel() {
    const int bv = blockIdx.x * 256 + threadIdx.x;   // 0..8191
    double n = fmax(sqrt(g_nn2[bv]), 1e-12);

    double D[NK];
#pragma unroll
    for (int k = 0; k < NK; ++k) D[k] = g_Bk[k];
#pragma unroll
    for (int sc = 0; sc < 8; ++sc) {
#pragma unroll
        for (int k = 0; k < NK; ++k)
            D[k] += g_Dp[((size_t)sc * (BS * NV) + bv) * NK + k];
    }

    double p[NK], sum = 0.0;
#pragma unroll
    for (int k = 0; k < NK; ++k) {
        p[k] = exp((D[k] / n) / 0.05);
        sum += p[k];
    }
    unsigned int byte = 0;
#pragma unroll
    for (int k = 0; k < NK; ++k) {
        uint32_t i = (uint32_t)(k * (BS * NV) + bv);
        uint32_t y0, y1;
        threefry2x32_key7(0u, i, y0, y1);
        float u = bits_to_uniform(y0 ^ y1);
        if ((double)u < p[k] / sum) byte |= 1u << k;
    }
    g_bits[bv] = (unsigned char)byte;
}

// ---------------------------------------------------------------------------
// Write (unchanged): 268 MB broadcast, float4 stores — at HBM floor.
// ---------------------------------------------------------------------------
__global__ __launch_bounds__(256) void write_kernel(float* __restrict__ out) {
    const int t = threadIdx.x;
    const size_t r0 = (size_t)blockIdx.x * 8;
#pragma unroll
    for (int j = 0; j < 8; ++j) {
        size_t r = r0 + j;                      // r = (k*16+b)*512+v
        unsigned int bv = (unsigned int)(r & 8191u);
        unsigned int k  = (unsigned int)(r >> 13);
        float v = ((g_bits[bv] >> k) & 1u) ? 1.0f : 0.0f;
        float4 val = make_float4(v, v, v, v);
        ((float4*)(out + r * 1024))[t] = val;
    }
}

// ---------------------------------------------------------------------------
extern "C" void kernel_launch(void* const* d_in, const int* in_sizes, int n_in,
                              void* d_out, int out_size, void* d_ws, size_t ws_size,
                              hipStream_t stream) {
    const float* x    = (const float*)d_in[0];
    const float* W    = (const float*)d_in[1];
    const float* bias = (const float*)d_in[2];
    const float* ce   = (const float*)d_in[3];
    float* out = (float*)d_out;

    wt_kernel<<<dim3(16, 2), dim3(256), 0, stream>>>(W);
    prep_kernel<<<dim3(32), dim3(256), 0, stream>>>(W, bias, ce);
    gemm_kernel<<<dim3(16, 16), dim3(256), 0, stream>>>(x, bias);
    dkern<<<dim3(8, 16, 8), dim3(256), 0, stream>>>(x);
    finalize_kernel<<<dim3(32), dim3(256), 0, stream>>>();
    write_kernel<<<dim3(8192), dim3(256), 0, stream>>>(out);
}